// Round 15
// baseline (148.197 us; speedup 1.0000x reference)
//
#include <hip/hip_runtime.h>

#define N_ROWS 131072
#define DIM 64
#define KCODES 512
#define MARGIN 1e-4f
#define QCAP 16384

typedef __attribute__((ext_vector_type(8))) short bf16x8;
typedef __attribute__((ext_vector_type(4))) float f32x4;

// ws layout (4-byte words):
// [0..256)        lossp f32[256]           (zeroed)
// [256..4352)     hist8 u32[8][512]        (zeroed)
// [4352]          qcount u32               (zeroed)
// [4353..4360)    pad
// [4360..20744)   queue u32[QCAP]
// [20744..21256)  bnp f32[512]
// [21256..54024)  wfrag ushort[65536] B-fragment image:
//                 frag = cti*256 + q*64 + lane (16B units); q:0=hi k0,1=hi k1,2=lo k0,3=lo k1

__device__ __forceinline__ float sqr_nf(float x) {
    float s = x * x;
    asm("" : "+v"(s));   // numpy rounds the square before summing
    return s;
}

__device__ __forceinline__ unsigned short f2bf(float f) {  // RNE, finite data
    unsigned u = __float_as_uint(f);
    u += 0x7fffu + ((u >> 16) & 1u);
    return (unsigned short)(u >> 16);
}
__device__ __forceinline__ float bf2f(unsigned short b) {
    return __uint_as_float(((unsigned)b) << 16);
}

__device__ __forceinline__ void cvtpair(float4 a, float4 b, bf16x8& hi, bf16x8& lo) {
    float v[8] = {a.x, a.y, a.z, a.w, b.x, b.y, b.z, b.w};
#pragma unroll
    for (int j = 0; j < 8; ++j) {
        unsigned short h = f2bf(v[j]);
        hi[j] = (short)h;
        lo[j] = (short)f2bf(v[j] - bf2f(h));
    }
}
__device__ __forceinline__ float4 scl(float4 v, float s) {
    return make_float4(v.x * s, v.y * s, v.z * s, v.w * s);
}

// ---- precompute: W -> bf16 hi/lo B-fragment image + np-exact norms ---------
__global__ __launch_bounds__(256) void vq_wprep_k(
    const float* __restrict__ W, unsigned short* __restrict__ wfrag,
    float* __restrict__ bnp) {
    int code = blockIdx.x * 256 + threadIdx.x;   // 0..511
    float p[64];
#pragma unroll
    for (int i = 0; i < 16; ++i) {
        float4 v = reinterpret_cast<const float4*>(W)[code * 16 + i];
        p[i * 4 + 0] = v.x; p[i * 4 + 1] = v.y;
        p[i * 4 + 2] = v.z; p[i * 4 + 3] = v.w;
    }
    unsigned short hi[64], lo[64];
#pragma unroll
    for (int d = 0; d < 64; ++d) {
        hi[d] = f2bf(p[d]);
        lo[d] = f2bf(p[d] - bf2f(hi[d]));
    }
    {   // np pairwise codeword norm  [validated rounds 3-14, absmax 0]
        float r[8];
#pragma unroll
        for (int j = 0; j < 8; ++j) r[j] = sqr_nf(p[j]);
#pragma unroll
        for (int i = 1; i < 8; ++i)
#pragma unroll
            for (int j = 0; j < 8; ++j) r[j] += sqr_nf(p[i * 8 + j]);
        bnp[code] = ((r[0] + r[1]) + (r[2] + r[3])) + ((r[4] + r[5]) + (r[6] + r[7]));
    }
    const int cti = code >> 4, m = code & 15;
#pragma unroll
    for (int part = 0; part < 2; ++part) {
        const unsigned short* src = part ? lo : hi;
#pragma unroll
        for (int s = 0; s < 2; ++s) {
            int q = part * 2 + s;
#pragma unroll
            for (int kq = 0; kq < 4; ++kq) {
                int lane = kq * 16 + m;
                size_t off = ((size_t)(cti * 4 + q) * 64 + lane) * 8;
                *reinterpret_cast<uint4*>(wfrag + off) =
                    *reinterpret_cast<const uint4*>(src + s * 32 + kq * 8);
            }
        }
    }
}

// ---- K1 v3: rt=2, 2-deep named-reg prefetch, bnp in LDS, 4+2 chains --------
#define SCORE_STEP(CTI, B0, B1, B2, B3)                                           \
    {                                                                             \
        const int kk = (CTI) * 16 + m;                                            \
        const float wn = bnp_s[kk];                                               \
        _Pragma("unroll")                                                         \
        for (int rt = 0; rt < 2; ++rt) {                                          \
            f32x4 c0 = {wn, wn, wn, wn};                                          \
            f32x4 c1 = {0.f, 0.f, 0.f, 0.f};                                      \
            c0 = __builtin_amdgcn_mfma_f32_16x16x32_bf16(ahi[rt][0], B0, c0, 0, 0, 0); \
            c1 = __builtin_amdgcn_mfma_f32_16x16x32_bf16(ahi[rt][0], B2, c1, 0, 0, 0); \
            c0 = __builtin_amdgcn_mfma_f32_16x16x32_bf16(alo[rt][0], B0, c0, 0, 0, 0); \
            c1 = __builtin_amdgcn_mfma_f32_16x16x32_bf16(ahi[rt][1], B3, c1, 0, 0, 0); \
            c0 = __builtin_amdgcn_mfma_f32_16x16x32_bf16(ahi[rt][1], B1, c0, 0, 0, 0); \
            c0 = __builtin_amdgcn_mfma_f32_16x16x32_bf16(alo[rt][1], B1, c0, 0, 0, 0); \
            f32x4 acc = c0 + c1;                                                  \
            _Pragma("unroll")                                                     \
            for (int j = 0; j < 4; ++j) {                                         \
                float s = acc[j];                                                 \
                float nb = fminf(best[rt][j], s);                                 \
                float ns = fminf(sec[rt][j], fmaxf(best[rt][j], s));              \
                bidx[rt][j] = (s < best[rt][j]) ? kk : bidx[rt][j];               \
                best[rt][j] = nb; sec[rt][j] = ns;                                \
            }                                                                     \
        }                                                                         \
    }

__global__ __launch_bounds__(256, 4) void vq_score_k(
    const float* __restrict__ X, const unsigned short* __restrict__ wfrag,
    const float* __restrict__ bnp, float* __restrict__ out_idx) {
    __shared__ float bnp_s[KCODES];
    const int tid = threadIdx.x;
    const int lane = tid & 63, w = tid >> 6;
    const int m = lane & 15, kq = lane >> 4;
    const long rbase = (long)blockIdx.x * 128;

    bnp_s[tid] = bnp[tid];
    bnp_s[256 + tid] = bnp[256 + tid];

    // A-fragments hold -2x (exact scale): lane (m,kq) holds A[m][kq*8+j]
    bf16x8 ahi[2][2], alo[2][2];
#pragma unroll
    for (int rt = 0; rt < 2; ++rt) {
        long row = rbase + w * 32 + rt * 16 + m;
        const float4* xp = reinterpret_cast<const float4*>(X + row * DIM);
        cvtpair(scl(xp[kq * 2], -2.f), scl(xp[kq * 2 + 1], -2.f),
                ahi[rt][0], alo[rt][0]);
        cvtpair(scl(xp[8 + kq * 2], -2.f), scl(xp[8 + kq * 2 + 1], -2.f),
                ahi[rt][1], alo[rt][1]);
    }
    __syncthreads();   // bnp_s ready

    float best[2][4], sec[2][4];
    int bidx[2][4];
#pragma unroll
    for (int rt = 0; rt < 2; ++rt)
#pragma unroll
        for (int j = 0; j < 4; ++j) { best[rt][j] = 3e38f; sec[rt][j] = 3e38f; bidx[rt][j] = 0; }

    const bf16x8* fb = reinterpret_cast<const bf16x8*>(wfrag);
    // 2-deep prefetch with NAMED registers (runtime-indexed arrays spill)
    bf16x8 pa0 = fb[lane], pa1 = fb[64 + lane], pa2 = fb[128 + lane], pa3 = fb[192 + lane];
    bf16x8 pb0 = fb[256 + lane], pb1 = fb[320 + lane], pb2 = fb[384 + lane], pb3 = fb[448 + lane];

    for (int cti = 0; cti < 32; cti += 2) {
        {   // even cti: consume pa, refill for cti+2
            bf16x8 b0 = pa0, b1 = pa1, b2 = pa2, b3 = pa3;
            if (cti + 2 < 32) {
                int nb = (cti + 2) * 256;
                pa0 = fb[nb + lane];       pa1 = fb[nb + 64 + lane];
                pa2 = fb[nb + 128 + lane]; pa3 = fb[nb + 192 + lane];
            }
            SCORE_STEP(cti, b0, b1, b2, b3);
        }
        {   // odd cti: consume pb, refill for cti+3
            bf16x8 b0 = pb0, b1 = pb1, b2 = pb2, b3 = pb3;
            if (cti + 3 < 32) {
                int nb = (cti + 3) * 256;
                pb0 = fb[nb + lane];       pb1 = fb[nb + 64 + lane];
                pb2 = fb[nb + 128 + lane]; pb3 = fb[nb + 192 + lane];
            }
            SCORE_STEP(cti + 1, b0, b1, b2, b3);
        }
    }

    // merge across the 16 m-lanes; exact ties -> smaller index
#pragma unroll
    for (int st = 1; st < 16; st <<= 1) {
#pragma unroll
        for (int rt = 0; rt < 2; ++rt)
#pragma unroll
            for (int j = 0; j < 4; ++j) {
                float ob = __shfl_xor(best[rt][j], st);
                float os = __shfl_xor(sec[rt][j], st);
                int oi = __shfl_xor(bidx[rt][j], st);
                if (ob < best[rt][j] || (ob == best[rt][j] && oi < bidx[rt][j])) {
                    sec[rt][j] = fminf(best[rt][j], os);
                    best[rt][j] = ob; bidx[rt][j] = oi;
                } else {
                    sec[rt][j] = fminf(sec[rt][j], ob);
                }
            }
    }

    if (m == 0) {   // C/D row = kq*4 + j
#pragma unroll
        for (int rt = 0; rt < 2; ++rt)
#pragma unroll
            for (int j = 0; j < 4; ++j) {
                int r = w * 32 + rt * 16 + kq * 4 + j;
                int id = (sec[rt][j] - best[rt][j] <= MARGIN) ? -1 : bidx[rt][j];
                out_idx[rbase + r] = (float)id;
            }
    }
}

// ---- K2a: bulk epilogue; flagged rows -> queue (no inline refine) ----------
__global__ __launch_bounds__(256, 4) void vq_post_k(
    const float* __restrict__ X, const float* __restrict__ Wf,
    const float* __restrict__ bnp,
    float* __restrict__ out_q, float* __restrict__ out_idx,
    unsigned* __restrict__ hist8, float* __restrict__ lossp,
    unsigned* __restrict__ qcount, unsigned* __restrict__ queue) {
    const int tid = threadIdx.x;
    const int lane = tid & 63, w = tid >> 6;
    const int g = lane >> 4, l16 = lane & 15;
    const long wbase = ((long)blockIdx.x * 4 + w) * 32;   // 32 rows per wave
    const unsigned hstripe = (blockIdx.x & 7) * KCODES;

    float idxv = (lane < 32) ? out_idx[wbase + lane] : 1.0f;

    // append flagged rows to the global refine queue
    int mypos = -1;
    if (lane < 32 && idxv < 0.f) {
        mypos = (int)atomicAdd(qcount, 1u);
        if (mypos < QCAP) queue[mypos] = (unsigned)(wbase + lane);
    }

    float4 xv[8], wv[8];
    int kk[8];
#pragma unroll
    for (int i = 0; i < 8; ++i) {
        int r = g * 8 + i;
        float kf = __shfl(idxv, r);
        kk[i] = (kf >= 0.f) ? (int)kf : -1;
        xv[i] = reinterpret_cast<const float4*>(X)[(wbase + r) * 16 + l16];
        int ksafe = (kk[i] >= 0) ? kk[i] : 0;
        wv[i] = reinterpret_cast<const float4*>(Wf)[(long)ksafe * 16 + l16];
    }

    float ls = 0.f;
#pragma unroll
    for (int i = 0; i < 8; ++i) {
        if (kk[i] >= 0) {
            float4 o; float t;
            t = wv[i].x - xv[i].x; o.x = xv[i].x + t; ls = fmaf(t, t, ls);
            t = wv[i].y - xv[i].y; o.y = xv[i].y + t; ls = fmaf(t, t, ls);
            t = wv[i].z - xv[i].z; o.z = xv[i].z + t; ls = fmaf(t, t, ls);
            t = wv[i].w - xv[i].w; o.w = xv[i].w + t; ls = fmaf(t, t, ls);
            reinterpret_cast<float4*>(out_q)[(wbase + g * 8 + i) * 16 + l16] = o;
            if (l16 == 0) atomicAdd(&hist8[hstripe + kk[i]], 1u);
        }
    }

    // queue-overflow fallback only (expected never): inline np-exact resolve
    unsigned long long inl = __ballot(mypos >= QCAP);
    while (inl) {
        const int b = __ffsll((long long)inl) - 1;
        inl &= inl - 1;
        const long rrow = wbase + b;
        const float xvv = X[rrow * DIM + lane];
        float sq = sqr_nf(xvv);
        float rr = sq;
#pragma unroll
        for (int t2 = 1; t2 < 8; ++t2) rr += __shfl(sq, (lane & 7) + 8 * t2);
        float t01 = rr + __shfl_xor(rr, 1);
        float t03 = t01 + __shfl_xor(t01, 2);
        float Afull = t03 + __shfl_xor(t03, 4);
        const float A = __shfl(Afull, 0);
        float acc[8];
#pragma unroll
        for (int c = 0; c < 8; ++c) acc[c] = 0.f;
        for (int d0 = 0; d0 < 16; ++d0) {
            float x0 = __shfl(xvv, d0 * 4 + 0);
            float x1 = __shfl(xvv, d0 * 4 + 1);
            float x2 = __shfl(xvv, d0 * 4 + 2);
            float x3 = __shfl(xvv, d0 * 4 + 3);
#pragma unroll
            for (int c = 0; c < 8; ++c) {
                float4 wq = *reinterpret_cast<const float4*>(
                    &Wf[(lane * 8 + c) * DIM + d0 * 4]);
                acc[c] = fmaf(x0, wq.x, acc[c]);
                acc[c] = fmaf(x1, wq.y, acc[c]);
                acc[c] = fmaf(x2, wq.z, acc[c]);
                acc[c] = fmaf(x3, wq.w, acc[c]);
            }
        }
        float bs = 3e38f;
        int bi = 0;
#pragma unroll
        for (int c = 0; c < 8; ++c) {
            int kkk = lane * 8 + c;
            float u = A + bnp[kkk];
            float s2 = u - 2.0f * acc[c];
            if (s2 < bs) { bs = s2; bi = kkk; }
        }
#pragma unroll
        for (int st = 1; st < 64; st <<= 1) {
            float ob = __shfl_xor(bs, st);
            int oi = __shfl_xor(bi, st);
            if (ob < bs || (ob == bs && oi < bi)) { bs = ob; bi = oi; }
        }
        const int k = bi;
        if (lane == 0) {
            out_idx[rrow] = (float)k;
            atomicAdd(&hist8[hstripe + k], 1u);
        }
        float qv = Wf[k * DIM + lane];
        float diff = qv - xvv;
        out_q[rrow * DIM + lane] = xvv + diff;
        ls = fmaf(diff, diff, ls);
    }

#pragma unroll
    for (int st = 1; st < 64; st <<= 1) ls += __shfl_xor(ls, st);
    if (lane == 0 && ls != 0.f) atomicAdd(&lossp[blockIdx.x & 255], ls);
}

// ---- K2b: load-balanced np-exact refine, W^T in LDS (coalesced) -----------
#define WTP 516   // padded row stride (floats): read-side conflict-free
__global__ __launch_bounds__(1024) void vq_refine_k(
    const float* __restrict__ X, const float* __restrict__ Wf,
    const float* __restrict__ bnp,
    float* __restrict__ out_q, float* __restrict__ out_idx,
    unsigned* __restrict__ hist8, float* __restrict__ lossp,
    const unsigned* __restrict__ qcount, const unsigned* __restrict__ queue) {
    __shared__ float WT[64 * WTP];   // WT[d][k] = W[k][d], 132KB
    const int tid = threadIdx.x;
    const int lane = tid & 63, wv = tid >> 6;

    // stage W transposed: coalesced global read, LDS scatter
#pragma unroll
    for (int i = 0; i < 8; ++i) {
        int f = i * 1024 + tid;              // flat float4 index
        int k = f >> 4, c4 = f & 15;
        float4 v = reinterpret_cast<const float4*>(Wf)[f];
        WT[(c4 * 4 + 0) * WTP + k] = v.x;
        WT[(c4 * 4 + 1) * WTP + k] = v.y;
        WT[(c4 * 4 + 2) * WTP + k] = v.z;
        WT[(c4 * 4 + 3) * WTP + k] = v.w;
    }
    __syncthreads();

    unsigned n = *qcount;
    if (n > QCAP) n = QCAP;
    const int gwave = blockIdx.x * 16 + wv;

    float ls = 0.f;
    for (unsigned j = gwave; j < n; j += 256 * 16) {
        const long row = (long)queue[j];
        const float xv = X[row * DIM + lane];   // lane d holds x[d]
        // A = np pairwise sumsq (shfl tree) [validated rounds 3-14]
        float sq = sqr_nf(xv);
        float rr = sq;
#pragma unroll
        for (int t2 = 1; t2 < 8; ++t2) rr += __shfl(sq, (lane & 7) + 8 * t2);
        float t01 = rr + __shfl_xor(rr, 1);
        float t03 = t01 + __shfl_xor(t01, 2);
        float Afull = t03 + __shfl_xor(t03, 4);
        const float A = __shfl(Afull, 0);
        // dots: lane owns codes k = c*64 + lane; sequential d ascending (np/BLAS)
        float acc[8];
#pragma unroll
        for (int c = 0; c < 8; ++c) acc[c] = 0.f;
        for (int d = 0; d < 64; ++d) {
            float xd = __shfl(xv, d);
#pragma unroll
            for (int c = 0; c < 8; ++c)
                acc[c] = fmaf(xd, WT[d * WTP + c * 64 + lane], acc[c]);
        }
        float bs = 3e38f;
        int bi = 0;
#pragma unroll
        for (int c = 0; c < 8; ++c) {
            int k = c * 64 + lane;              // ascending within lane
            float u = A + bnp[k];
            float s2 = u - 2.0f * acc[c];
            if (s2 < bs) { bs = s2; bi = k; }   // strict < keeps first
        }
#pragma unroll
        for (int st = 1; st < 64; st <<= 1) {   // ties -> smaller index
            float ob = __shfl_xor(bs, st);
            int oi = __shfl_xor(bi, st);
            if (ob < bs || (ob == bs && oi < bi)) { bs = ob; bi = oi; }
        }
        const int k = bi;
        if (lane == 0) {
            out_idx[row] = (float)k;
            atomicAdd(&hist8[(j & 7) * KCODES + k], 1u);
        }
        float qv = WT[lane * WTP + k];          // W[k][lane]
        float diff = qv - xv;
        out_q[row * DIM + lane] = xv + diff;
        ls = fmaf(diff, diff, ls);
    }

#pragma unroll
    for (int st = 1; st < 64; st <<= 1) ls += __shfl_xor(ls, st);
    if (lane == 0 && ls != 0.f) atomicAdd(&lossp[gwave & 255], ls);
}

__global__ __launch_bounds__(512) void vq_finalize_k(
    const unsigned* __restrict__ hist8, const float* __restrict__ lossp,
    float* __restrict__ out_loss, float* __restrict__ out_perp) {
    __shared__ float red[512];
    int t = threadIdx.x;
    unsigned c = 0;
#pragma unroll
    for (int s = 0; s < 8; ++s) c += hist8[s * KCODES + t];
    float p = (float)c * (1.0f / (float)N_ROWS);
    red[t] = p * logf(p + 1e-10f);
    __syncthreads();
    for (int off = 256; off; off >>= 1) {
        if (t < off) red[t] += red[t + off];
        __syncthreads();
    }
    if (t == 0) *out_perp = expf(-red[0]);
    __syncthreads();
    red[t] = (t < 256) ? lossp[t] : 0.f;
    __syncthreads();
    for (int off = 256; off; off >>= 1) {
        if (t < off) red[t] += red[t + off];
        __syncthreads();
    }
    if (t == 0) {
        float m = red[0] / (float)(N_ROWS * DIM);
        *out_loss = m + 0.25f * m;
    }
}

extern "C" void kernel_launch(void* const* d_in, const int* in_sizes, int n_in,
                              void* d_out, int out_size, void* d_ws, size_t ws_size,
                              hipStream_t stream) {
    const float* X = (const float*)d_in[0];
    const float* Wf = (const float*)d_in[1];

    float* out = (float*)d_out;
    float* out_loss = out;
    float* out_q = out + 1;
    float* out_perp = out + 1 + (long)N_ROWS * DIM;
    float* out_idx = out + 2 + (long)N_ROWS * DIM;

    unsigned* wsu = (unsigned*)d_ws;
    float* lossp = (float*)d_ws;                    // [0..256)
    unsigned* hist8 = wsu + 256;                    // [256..4352)
    unsigned* qcount = wsu + 4352;                  // [4352]
    unsigned* queue = wsu + 4360;                   // [4360..20744)
    float* bnp = (float*)(wsu + 20744);             // [20744..21256)
    unsigned short* wfrag = (unsigned short*)(wsu + 21256);  // [21256..54024)

    hipMemsetAsync(d_ws, 0, 17412, stream);         // lossp + hist8 + qcount
    vq_wprep_k<<<2, 256, 0, stream>>>(Wf, wfrag, bnp);
    vq_score_k<<<N_ROWS / 128, 256, 0, stream>>>(X, wfrag, bnp, out_idx);
    vq_post_k<<<N_ROWS / 128, 256, 0, stream>>>(X, Wf, bnp, out_q, out_idx,
                                                hist8, lossp, qcount, queue);
    vq_refine_k<<<256, 1024, 0, stream>>>(X, Wf, bnp, out_q, out_idx,
                                          hist8, lossp, qcount, queue);
    vq_finalize_k<<<1, 512, 0, stream>>>(hist8, lossp, out_loss, out_perp);
}

// Round 16
// 112.213 us; speedup vs baseline: 1.3207x; 1.3207x over previous
//
#include <hip/hip_runtime.h>

#define N_ROWS 131072
#define DIM 64
#define KCODES 512
#define MARGIN 1e-4f
#define QCAP 16384

typedef __attribute__((ext_vector_type(8))) short bf16x8;
typedef __attribute__((ext_vector_type(4))) float f32x4;

// ws layout (4-byte words):
// [0..256)        lossp f32[256]           (zeroed)
// [256..4352)     hist8 u32[8][512]        (zeroed)
// [4352]          qcount u32               (zeroed)
// [4353..4360)    pad
// [4360..20744)   queue u32[QCAP]
// [20744..21256)  bnp f32[512]
// [21256..54024)  wfrag ushort[65536] B-fragment image:
//                 frag = cti*256 + q*64 + lane (16B units); q:0=hi k0,1=hi k1,2=lo k0,3=lo k1

__device__ __forceinline__ float sqr_nf(float x) {
    float s = x * x;
    asm("" : "+v"(s));   // numpy rounds the square before summing
    return s;
}

__device__ __forceinline__ unsigned short f2bf(float f) {  // RNE, finite data
    unsigned u = __float_as_uint(f);
    u += 0x7fffu + ((u >> 16) & 1u);
    return (unsigned short)(u >> 16);
}
__device__ __forceinline__ float bf2f(unsigned short b) {
    return __uint_as_float(((unsigned)b) << 16);
}

__device__ __forceinline__ void cvtpair(float4 a, float4 b, bf16x8& hi, bf16x8& lo) {
    float v[8] = {a.x, a.y, a.z, a.w, b.x, b.y, b.z, b.w};
#pragma unroll
    for (int j = 0; j < 8; ++j) {
        unsigned short h = f2bf(v[j]);
        hi[j] = (short)h;
        lo[j] = (short)f2bf(v[j] - bf2f(h));
    }
}
__device__ __forceinline__ float4 scl(float4 v, float s) {
    return make_float4(v.x * s, v.y * s, v.z * s, v.w * s);
}

// ---- precompute: W -> bf16 hi/lo B-fragment image + np-exact norms ---------
__global__ __launch_bounds__(256) void vq_wprep_k(
    const float* __restrict__ W, unsigned short* __restrict__ wfrag,
    float* __restrict__ bnp) {
    int code = blockIdx.x * 256 + threadIdx.x;   // 0..511
    float p[64];
#pragma unroll
    for (int i = 0; i < 16; ++i) {
        float4 v = reinterpret_cast<const float4*>(W)[code * 16 + i];
        p[i * 4 + 0] = v.x; p[i * 4 + 1] = v.y;
        p[i * 4 + 2] = v.z; p[i * 4 + 3] = v.w;
    }
    unsigned short hi[64], lo[64];
#pragma unroll
    for (int d = 0; d < 64; ++d) {
        hi[d] = f2bf(p[d]);
        lo[d] = f2bf(p[d] - bf2f(hi[d]));
    }
    {   // np pairwise codeword norm  [validated rounds 3-15, absmax 0]
        float r[8];
#pragma unroll
        for (int j = 0; j < 8; ++j) r[j] = sqr_nf(p[j]);
#pragma unroll
        for (int i = 1; i < 8; ++i)
#pragma unroll
            for (int j = 0; j < 8; ++j) r[j] += sqr_nf(p[i * 8 + j]);
        bnp[code] = ((r[0] + r[1]) + (r[2] + r[3])) + ((r[4] + r[5]) + (r[6] + r[7]));
    }
    const int cti = code >> 4, m = code & 15;
#pragma unroll
    for (int part = 0; part < 2; ++part) {
        const unsigned short* src = part ? lo : hi;
#pragma unroll
        for (int s = 0; s < 2; ++s) {
            int q = part * 2 + s;
#pragma unroll
            for (int kq = 0; kq < 4; ++kq) {
                int lane = kq * 16 + m;
                size_t off = ((size_t)(cti * 4 + q) * 64 + lane) * 8;
                *reinterpret_cast<uint4*>(wfrag + off) =
                    *reinterpret_cast<const uint4*>(src + s * 32 + kq * 8);
            }
        }
    }
}

// ---- K1 v4: full B image in LDS (staged once), 16 waves, barrier-free loop -
__global__ __launch_bounds__(1024, 4) void vq_score_k(
    const float* __restrict__ X, const unsigned short* __restrict__ wfrag,
    const float* __restrict__ bnp, float* __restrict__ out_idx) {
    __shared__ __align__(16) unsigned short Wlds[65536];  // 128 KB image
    __shared__ float bnp_s[KCODES];
    const int tid = threadIdx.x;
    const int lane = tid & 63, w = tid >> 6;   // 16 waves
    const int m = lane & 15, kq = lane >> 4;
    const long rbase = (long)blockIdx.x * 512;

    // stage full image once (linear copy; reads hit L2, 32MB total grid-wide)
    {
        const uint4* g = reinterpret_cast<const uint4*>(wfrag);
        uint4* l4 = reinterpret_cast<uint4*>(Wlds);
#pragma unroll
        for (int i = 0; i < 8; ++i) l4[i * 1024 + tid] = g[i * 1024 + tid];
    }
    if (tid < KCODES) bnp_s[tid] = bnp[tid];

    // A-fragments hold -2x (exact scale): lane (m,kq) holds A[m][kq*8+j]
    bf16x8 ahi[2][2], alo[2][2];
#pragma unroll
    for (int rt = 0; rt < 2; ++rt) {
        long row = rbase + w * 32 + rt * 16 + m;
        const float4* xp = reinterpret_cast<const float4*>(X + row * DIM);
        cvtpair(scl(xp[kq * 2], -2.f), scl(xp[kq * 2 + 1], -2.f),
                ahi[rt][0], alo[rt][0]);
        cvtpair(scl(xp[8 + kq * 2], -2.f), scl(xp[8 + kq * 2 + 1], -2.f),
                ahi[rt][1], alo[rt][1]);
    }
    __syncthreads();   // Wlds + bnp_s ready; no barriers after this

    float best[2][4], sec[2][4];
    int bidx[2][4];
#pragma unroll
    for (int rt = 0; rt < 2; ++rt)
#pragma unroll
        for (int j = 0; j < 4; ++j) { best[rt][j] = 3e38f; sec[rt][j] = 3e38f; bidx[rt][j] = 0; }

    const bf16x8* fp = reinterpret_cast<const bf16x8*>(Wlds);
    bf16x8 nb0 = fp[lane], nb1 = fp[64 + lane], nb2 = fp[128 + lane], nb3 = fp[192 + lane];
    for (int cti = 0; cti < 32; ++cti) {
        bf16x8 b0 = nb0, b1 = nb1, b2 = nb2, b3 = nb3;
        if (cti < 31) {
            int nbi = (cti + 1) * 256;
            nb0 = fp[nbi + lane];       nb1 = fp[nbi + 64 + lane];
            nb2 = fp[nbi + 128 + lane]; nb3 = fp[nbi + 192 + lane];
        }
        const int kk = cti * 16 + m;
        const float wn = bnp_s[kk];
        // score = wn + sum((-2x)*w); per rt: 4-chain (hh+lh) + 2-chain (hl)
#pragma unroll
        for (int rt = 0; rt < 2; ++rt) {
            f32x4 c0 = {wn, wn, wn, wn};
            f32x4 c1 = {0.f, 0.f, 0.f, 0.f};
            c0 = __builtin_amdgcn_mfma_f32_16x16x32_bf16(ahi[rt][0], b0, c0, 0, 0, 0);
            c1 = __builtin_amdgcn_mfma_f32_16x16x32_bf16(ahi[rt][0], b2, c1, 0, 0, 0);
            c0 = __builtin_amdgcn_mfma_f32_16x16x32_bf16(alo[rt][0], b0, c0, 0, 0, 0);
            c1 = __builtin_amdgcn_mfma_f32_16x16x32_bf16(ahi[rt][1], b3, c1, 0, 0, 0);
            c0 = __builtin_amdgcn_mfma_f32_16x16x32_bf16(ahi[rt][1], b1, c0, 0, 0, 0);
            c0 = __builtin_amdgcn_mfma_f32_16x16x32_bf16(alo[rt][1], b1, c0, 0, 0, 0);
            f32x4 acc = c0 + c1;
#pragma unroll
            for (int j = 0; j < 4; ++j) {
                float s = acc[j];
                float nb = fminf(best[rt][j], s);
                float ns = fminf(sec[rt][j], fmaxf(best[rt][j], s));
                bidx[rt][j] = (s < best[rt][j]) ? kk : bidx[rt][j];
                best[rt][j] = nb; sec[rt][j] = ns;
            }
        }
    }

    // merge across the 16 m-lanes; exact ties -> smaller index
#pragma unroll
    for (int st = 1; st < 16; st <<= 1) {
#pragma unroll
        for (int rt = 0; rt < 2; ++rt)
#pragma unroll
            for (int j = 0; j < 4; ++j) {
                float ob = __shfl_xor(best[rt][j], st);
                float os = __shfl_xor(sec[rt][j], st);
                int oi = __shfl_xor(bidx[rt][j], st);
                if (ob < best[rt][j] || (ob == best[rt][j] && oi < bidx[rt][j])) {
                    sec[rt][j] = fminf(best[rt][j], os);
                    best[rt][j] = ob; bidx[rt][j] = oi;
                } else {
                    sec[rt][j] = fminf(sec[rt][j], ob);
                }
            }
    }

    if (m == 0) {   // C/D row = kq*4 + j
#pragma unroll
        for (int rt = 0; rt < 2; ++rt)
#pragma unroll
            for (int j = 0; j < 4; ++j) {
                int r = w * 32 + rt * 16 + kq * 4 + j;
                int id = (sec[rt][j] - best[rt][j] <= MARGIN) ? -1 : bidx[rt][j];
                out_idx[rbase + r] = (float)id;
            }
    }
}

// ---- K2a: bulk epilogue; flagged rows -> queue (no inline refine) ----------
__global__ __launch_bounds__(256, 4) void vq_post_k(
    const float* __restrict__ X, const float* __restrict__ Wf,
    const float* __restrict__ bnp,
    float* __restrict__ out_q, float* __restrict__ out_idx,
    unsigned* __restrict__ hist8, float* __restrict__ lossp,
    unsigned* __restrict__ qcount, unsigned* __restrict__ queue) {
    const int tid = threadIdx.x;
    const int lane = tid & 63, w = tid >> 6;
    const int g = lane >> 4, l16 = lane & 15;
    const long wbase = ((long)blockIdx.x * 4 + w) * 32;   // 32 rows per wave
    const unsigned hstripe = (blockIdx.x & 7) * KCODES;

    float idxv = (lane < 32) ? out_idx[wbase + lane] : 1.0f;

    // append flagged rows to the global refine queue
    int mypos = -1;
    if (lane < 32 && idxv < 0.f) {
        mypos = (int)atomicAdd(qcount, 1u);
        if (mypos < QCAP) queue[mypos] = (unsigned)(wbase + lane);
    }

    float4 xv[8], wv[8];
    int kk[8];
#pragma unroll
    for (int i = 0; i < 8; ++i) {
        int r = g * 8 + i;
        float kf = __shfl(idxv, r);
        kk[i] = (kf >= 0.f) ? (int)kf : -1;
        xv[i] = reinterpret_cast<const float4*>(X)[(wbase + r) * 16 + l16];
        int ksafe = (kk[i] >= 0) ? kk[i] : 0;
        wv[i] = reinterpret_cast<const float4*>(Wf)[(long)ksafe * 16 + l16];
    }

    float ls = 0.f;
#pragma unroll
    for (int i = 0; i < 8; ++i) {
        if (kk[i] >= 0) {
            float4 o; float t;
            t = wv[i].x - xv[i].x; o.x = xv[i].x + t; ls = fmaf(t, t, ls);
            t = wv[i].y - xv[i].y; o.y = xv[i].y + t; ls = fmaf(t, t, ls);
            t = wv[i].z - xv[i].z; o.z = xv[i].z + t; ls = fmaf(t, t, ls);
            t = wv[i].w - xv[i].w; o.w = xv[i].w + t; ls = fmaf(t, t, ls);
            reinterpret_cast<float4*>(out_q)[(wbase + g * 8 + i) * 16 + l16] = o;
            if (l16 == 0) atomicAdd(&hist8[hstripe + kk[i]], 1u);
        }
    }

    // queue-overflow fallback only (expected never): inline np-exact resolve
    unsigned long long inl = __ballot(mypos >= QCAP);
    while (inl) {
        const int b = __ffsll((long long)inl) - 1;
        inl &= inl - 1;
        const long rrow = wbase + b;
        const float xvv = X[rrow * DIM + lane];
        float sq = sqr_nf(xvv);
        float rr = sq;
#pragma unroll
        for (int t2 = 1; t2 < 8; ++t2) rr += __shfl(sq, (lane & 7) + 8 * t2);
        float t01 = rr + __shfl_xor(rr, 1);
        float t03 = t01 + __shfl_xor(t01, 2);
        float Afull = t03 + __shfl_xor(t03, 4);
        const float A = __shfl(Afull, 0);
        float acc[8];
#pragma unroll
        for (int c = 0; c < 8; ++c) acc[c] = 0.f;
        for (int d0 = 0; d0 < 16; ++d0) {
            float x0 = __shfl(xvv, d0 * 4 + 0);
            float x1 = __shfl(xvv, d0 * 4 + 1);
            float x2 = __shfl(xvv, d0 * 4 + 2);
            float x3 = __shfl(xvv, d0 * 4 + 3);
#pragma unroll
            for (int c = 0; c < 8; ++c) {
                float4 wq = *reinterpret_cast<const float4*>(
                    &Wf[(lane * 8 + c) * DIM + d0 * 4]);
                acc[c] = fmaf(x0, wq.x, acc[c]);
                acc[c] = fmaf(x1, wq.y, acc[c]);
                acc[c] = fmaf(x2, wq.z, acc[c]);
                acc[c] = fmaf(x3, wq.w, acc[c]);
            }
        }
        float bs = 3e38f;
        int bi = 0;
#pragma unroll
        for (int c = 0; c < 8; ++c) {
            int kkk = lane * 8 + c;
            float u = A + bnp[kkk];
            float s2 = u - 2.0f * acc[c];
            if (s2 < bs) { bs = s2; bi = kkk; }
        }
#pragma unroll
        for (int st = 1; st < 64; st <<= 1) {
            float ob = __shfl_xor(bs, st);
            int oi = __shfl_xor(bi, st);
            if (ob < bs || (ob == bs && oi < bi)) { bs = ob; bi = oi; }
        }
        const int k = bi;
        if (lane == 0) {
            out_idx[rrow] = (float)k;
            atomicAdd(&hist8[hstripe + k], 1u);
        }
        float qv = Wf[k * DIM + lane];
        float diff = qv - xvv;
        out_q[rrow * DIM + lane] = xvv + diff;
        ls = fmaf(diff, diff, ls);
    }

#pragma unroll
    for (int st = 1; st < 64; st <<= 1) ls += __shfl_xor(ls, st);
    if (lane == 0 && ls != 0.f) atomicAdd(&lossp[blockIdx.x & 255], ls);
}

// ---- K2b: load-balanced np-exact refine, W^T in LDS (coalesced) -----------
#define WTP 516   // padded row stride (floats): read-side conflict-free
__global__ __launch_bounds__(1024) void vq_refine_k(
    const float* __restrict__ X, const float* __restrict__ Wf,
    const float* __restrict__ bnp,
    float* __restrict__ out_q, float* __restrict__ out_idx,
    unsigned* __restrict__ hist8, float* __restrict__ lossp,
    const unsigned* __restrict__ qcount, const unsigned* __restrict__ queue) {
    __shared__ float WT[64 * WTP];   // WT[d][k] = W[k][d], 132KB
    const int tid = threadIdx.x;
    const int lane = tid & 63, wv = tid >> 6;

    // stage W transposed: coalesced global read, LDS scatter
#pragma unroll
    for (int i = 0; i < 8; ++i) {
        int f = i * 1024 + tid;              // flat float4 index
        int k = f >> 4, c4 = f & 15;
        float4 v = reinterpret_cast<const float4*>(Wf)[f];
        WT[(c4 * 4 + 0) * WTP + k] = v.x;
        WT[(c4 * 4 + 1) * WTP + k] = v.y;
        WT[(c4 * 4 + 2) * WTP + k] = v.z;
        WT[(c4 * 4 + 3) * WTP + k] = v.w;
    }
    __syncthreads();

    unsigned n = *qcount;
    if (n > QCAP) n = QCAP;
    const int gwave = blockIdx.x * 16 + wv;

    float ls = 0.f;
    for (unsigned j = gwave; j < n; j += 256 * 16) {
        const long row = (long)queue[j];
        const float xv = X[row * DIM + lane];   // lane d holds x[d]
        // A = np pairwise sumsq (shfl tree) [validated rounds 3-15]
        float sq = sqr_nf(xv);
        float rr = sq;
#pragma unroll
        for (int t2 = 1; t2 < 8; ++t2) rr += __shfl(sq, (lane & 7) + 8 * t2);
        float t01 = rr + __shfl_xor(rr, 1);
        float t03 = t01 + __shfl_xor(t01, 2);
        float Afull = t03 + __shfl_xor(t03, 4);
        const float A = __shfl(Afull, 0);
        // dots: lane owns codes k = c*64 + lane; sequential d ascending (np/BLAS)
        float acc[8];
#pragma unroll
        for (int c = 0; c < 8; ++c) acc[c] = 0.f;
        for (int d = 0; d < 64; ++d) {
            float xd = __shfl(xv, d);
#pragma unroll
            for (int c = 0; c < 8; ++c)
                acc[c] = fmaf(xd, WT[d * WTP + c * 64 + lane], acc[c]);
        }
        float bs = 3e38f;
        int bi = 0;
#pragma unroll
        for (int c = 0; c < 8; ++c) {
            int k = c * 64 + lane;              // ascending within lane
            float u = A + bnp[k];
            float s2 = u - 2.0f * acc[c];
            if (s2 < bs) { bs = s2; bi = k; }   // strict < keeps first
        }
#pragma unroll
        for (int st = 1; st < 64; st <<= 1) {   // ties -> smaller index
            float ob = __shfl_xor(bs, st);
            int oi = __shfl_xor(bi, st);
            if (ob < bs || (ob == bs && oi < bi)) { bs = ob; bi = oi; }
        }
        const int k = bi;
        if (lane == 0) {
            out_idx[row] = (float)k;
            atomicAdd(&hist8[(j & 7) * KCODES + k], 1u);
        }
        float qv = WT[lane * WTP + k];          // W[k][lane]
        float diff = qv - xv;
        out_q[row * DIM + lane] = xv + diff;
        ls = fmaf(diff, diff, ls);
    }

#pragma unroll
    for (int st = 1; st < 64; st <<= 1) ls += __shfl_xor(ls, st);
    if (lane == 0 && ls != 0.f) atomicAdd(&lossp[gwave & 255], ls);
}

__global__ __launch_bounds__(512) void vq_finalize_k(
    const unsigned* __restrict__ hist8, const float* __restrict__ lossp,
    float* __restrict__ out_loss, float* __restrict__ out_perp) {
    __shared__ float red[512];
    int t = threadIdx.x;
    unsigned c = 0;
#pragma unroll
    for (int s = 0; s < 8; ++s) c += hist8[s * KCODES + t];
    float p = (float)c * (1.0f / (float)N_ROWS);
    red[t] = p * logf(p + 1e-10f);
    __syncthreads();
    for (int off = 256; off; off >>= 1) {
        if (t < off) red[t] += red[t + off];
        __syncthreads();
    }
    if (t == 0) *out_perp = expf(-red[0]);
    __syncthreads();
    red[t] = (t < 256) ? lossp[t] : 0.f;
    __syncthreads();
    for (int off = 256; off; off >>= 1) {
        if (t < off) red[t] += red[t + off];
        __syncthreads();
    }
    if (t == 0) {
        float m = red[0] / (float)(N_ROWS * DIM);
        *out_loss = m + 0.25f * m;
    }
}

extern "C" void kernel_launch(void* const* d_in, const int* in_sizes, int n_in,
                              void* d_out, int out_size, void* d_ws, size_t ws_size,
                              hipStream_t stream) {
    const float* X = (const float*)d_in[0];
    const float* Wf = (const float*)d_in[1];

    float* out = (float*)d_out;
    float* out_loss = out;
    float* out_q = out + 1;
    float* out_perp = out + 1 + (long)N_ROWS * DIM;
    float* out_idx = out + 2 + (long)N_ROWS * DIM;

    unsigned* wsu = (unsigned*)d_ws;
    float* lossp = (float*)d_ws;                    // [0..256)
    unsigned* hist8 = wsu + 256;                    // [256..4352)
    unsigned* qcount = wsu + 4352;                  // [4352]
    unsigned* queue = wsu + 4360;                   // [4360..20744)
    float* bnp = (float*)(wsu + 20744);             // [20744..21256)
    unsigned short* wfrag = (unsigned short*)(wsu + 21256);  // [21256..54024)

    hipMemsetAsync(d_ws, 0, 17412, stream);         // lossp + hist8 + qcount
    vq_wprep_k<<<2, 256, 0, stream>>>(Wf, wfrag, bnp);
    vq_score_k<<<N_ROWS / 512, 1024, 0, stream>>>(X, wfrag, bnp, out_idx);
    vq_post_k<<<N_ROWS / 128, 256, 0, stream>>>(X, Wf, bnp, out_q, out_idx,
                                                hist8, lossp, qcount, queue);
    vq_refine_k<<<256, 1024, 0, stream>>>(X, Wf, bnp, out_q, out_idx,
                                          hist8, lossp, qcount, queue);
    vq_finalize_k<<<1, 512, 0, stream>>>(hist8, lossp, out_loss, out_perp);
}

// Round 17
// 93.886 us; speedup vs baseline: 1.5785x; 1.1952x over previous
//
#include <hip/hip_runtime.h>

#define N_ROWS 131072
#define DIM 64
#define KCODES 512
#define MARGIN 1e-4f
#define QCAP 32768

typedef __attribute__((ext_vector_type(8))) short bf16x8;
typedef __attribute__((ext_vector_type(4))) float f32x4;

// ws layout (4-byte words):
// [0..256)        lossp f32[256]           (zeroed)
// [256..4352)     hist8 u32[8][512]        (zeroed)
// [4352]          qcount u32               (zeroed)
// [4353..4360)    pad
// [4360..37128)   queue u32[QCAP]
// [37128..37640)  bnp f32[512]
// [37640..70408)  wfrag ushort[65536] B-fragment image:
//                 frag = cti*256 + q*64 + lane (16B units); q:0=hi k0,1=hi k1,2=lo k0,3=lo k1

__device__ __forceinline__ float sqr_nf(float x) {
    float s = x * x;
    asm("" : "+v"(s));   // numpy rounds the square before summing
    return s;
}

__device__ __forceinline__ unsigned short f2bf(float f) {  // RNE, finite data
    unsigned u = __float_as_uint(f);
    u += 0x7fffu + ((u >> 16) & 1u);
    return (unsigned short)(u >> 16);
}
__device__ __forceinline__ float bf2f(unsigned short b) {
    return __uint_as_float(((unsigned)b) << 16);
}

__device__ __forceinline__ void cvtpair(float4 a, float4 b, bf16x8& hi, bf16x8& lo) {
    float v[8] = {a.x, a.y, a.z, a.w, b.x, b.y, b.z, b.w};
#pragma unroll
    for (int j = 0; j < 8; ++j) {
        unsigned short h = f2bf(v[j]);
        hi[j] = (short)h;
        lo[j] = (short)f2bf(v[j] - bf2f(h));
    }
}
__device__ __forceinline__ float4 scl(float4 v, float s) {
    return make_float4(v.x * s, v.y * s, v.z * s, v.w * s);
}

// ---- precompute: W -> bf16 hi/lo B-fragment image + np-exact norms ---------
__global__ __launch_bounds__(256) void vq_wprep_k(
    const float* __restrict__ W, unsigned short* __restrict__ wfrag,
    float* __restrict__ bnp) {
    int code = blockIdx.x * 256 + threadIdx.x;   // 0..511
    float p[64];
#pragma unroll
    for (int i = 0; i < 16; ++i) {
        float4 v = reinterpret_cast<const float4*>(W)[code * 16 + i];
        p[i * 4 + 0] = v.x; p[i * 4 + 1] = v.y;
        p[i * 4 + 2] = v.z; p[i * 4 + 3] = v.w;
    }
    unsigned short hi[64], lo[64];
#pragma unroll
    for (int d = 0; d < 64; ++d) {
        hi[d] = f2bf(p[d]);
        lo[d] = f2bf(p[d] - bf2f(hi[d]));
    }
    {   // np pairwise codeword norm  [validated rounds 3-16, absmax 0]
        float r[8];
#pragma unroll
        for (int j = 0; j < 8; ++j) r[j] = sqr_nf(p[j]);
#pragma unroll
        for (int i = 1; i < 8; ++i)
#pragma unroll
            for (int j = 0; j < 8; ++j) r[j] += sqr_nf(p[i * 8 + j]);
        bnp[code] = ((r[0] + r[1]) + (r[2] + r[3])) + ((r[4] + r[5]) + (r[6] + r[7]));
    }
    const int cti = code >> 4, m = code & 15;
#pragma unroll
    for (int part = 0; part < 2; ++part) {
        const unsigned short* src = part ? lo : hi;
#pragma unroll
        for (int s = 0; s < 2; ++s) {
            int q = part * 2 + s;
#pragma unroll
            for (int kq = 0; kq < 4; ++kq) {
                int lane = kq * 16 + m;
                size_t off = ((size_t)(cti * 4 + q) * 64 + lane) * 8;
                *reinterpret_cast<uint4*>(wfrag + off) =
                    *reinterpret_cast<const uint4*>(src + s * 32 + kq * 8);
            }
        }
    }
}

// ---- fused main: r13-proven score structure + in-wave epilogue -------------
__global__ __launch_bounds__(256, 4) void vq_main_k(
    const float* __restrict__ X, const float* __restrict__ Wf,
    const unsigned short* __restrict__ wfrag, const float* __restrict__ bnp,
    float* __restrict__ out_q, float* __restrict__ out_idx,
    unsigned* __restrict__ hist8, float* __restrict__ lossp,
    unsigned* __restrict__ qcount, unsigned* __restrict__ queue) {
    __shared__ int idx_s[128];
    const int tid = threadIdx.x;
    const int lane = tid & 63, w = tid >> 6;
    const int m = lane & 15, kq = lane >> 4;
    const long rbase = (long)blockIdx.x * 128;
    const unsigned hstripe = (blockIdx.x & 7) * KCODES;

    // ---- score section (byte-equivalent to the measured-best r13 kernel) ----
    bf16x8 ahi[2][2], alo[2][2];
#pragma unroll
    for (int rt = 0; rt < 2; ++rt) {
        long row = rbase + w * 32 + rt * 16 + m;
        const float4* xp = reinterpret_cast<const float4*>(X + row * DIM);
        cvtpair(scl(xp[kq * 2], -2.f), scl(xp[kq * 2 + 1], -2.f),
                ahi[rt][0], alo[rt][0]);
        cvtpair(scl(xp[8 + kq * 2], -2.f), scl(xp[8 + kq * 2 + 1], -2.f),
                ahi[rt][1], alo[rt][1]);
    }

    float best[2][4], sec[2][4];
    int bidx[2][4];
#pragma unroll
    for (int rt = 0; rt < 2; ++rt)
#pragma unroll
        for (int j = 0; j < 4; ++j) { best[rt][j] = 3e38f; sec[rt][j] = 3e38f; bidx[rt][j] = 0; }

    const bf16x8* fb = reinterpret_cast<const bf16x8*>(wfrag);
    bf16x8 nb0 = fb[lane], nb1 = fb[64 + lane], nb2 = fb[128 + lane], nb3 = fb[192 + lane];
    for (int cti = 0; cti < 32; ++cti) {
        bf16x8 b0 = nb0, b1 = nb1, b2 = nb2, b3 = nb3;
        if (cti < 31) {
            int nbase = (cti + 1) * 256;
            nb0 = fb[nbase + lane];       nb1 = fb[nbase + 64 + lane];
            nb2 = fb[nbase + 128 + lane]; nb3 = fb[nbase + 192 + lane];
        }
        const int kk = cti * 16 + m;
        const float wn = bnp[kk];
        f32x4 c0 = {wn, wn, wn, wn};
        f32x4 c1 = {wn, wn, wn, wn};
        c0 = __builtin_amdgcn_mfma_f32_16x16x32_bf16(ahi[0][0], b0, c0, 0, 0, 0);
        c1 = __builtin_amdgcn_mfma_f32_16x16x32_bf16(ahi[1][0], b0, c1, 0, 0, 0);
        c0 = __builtin_amdgcn_mfma_f32_16x16x32_bf16(ahi[0][1], b1, c0, 0, 0, 0);
        c1 = __builtin_amdgcn_mfma_f32_16x16x32_bf16(ahi[1][1], b1, c1, 0, 0, 0);
        c0 = __builtin_amdgcn_mfma_f32_16x16x32_bf16(alo[0][0], b0, c0, 0, 0, 0);
        c1 = __builtin_amdgcn_mfma_f32_16x16x32_bf16(alo[1][0], b0, c1, 0, 0, 0);
        c0 = __builtin_amdgcn_mfma_f32_16x16x32_bf16(alo[0][1], b1, c0, 0, 0, 0);
        c1 = __builtin_amdgcn_mfma_f32_16x16x32_bf16(alo[1][1], b1, c1, 0, 0, 0);
        c0 = __builtin_amdgcn_mfma_f32_16x16x32_bf16(ahi[0][0], b2, c0, 0, 0, 0);
        c1 = __builtin_amdgcn_mfma_f32_16x16x32_bf16(ahi[1][0], b2, c1, 0, 0, 0);
        c0 = __builtin_amdgcn_mfma_f32_16x16x32_bf16(ahi[0][1], b3, c0, 0, 0, 0);
        c1 = __builtin_amdgcn_mfma_f32_16x16x32_bf16(ahi[1][1], b3, c1, 0, 0, 0);
#pragma unroll
        for (int rt = 0; rt < 2; ++rt)
#pragma unroll
            for (int j = 0; j < 4; ++j) {
                float s = (rt == 0) ? c0[j] : c1[j];
                float nb = fminf(best[rt][j], s);
                float ns = fminf(sec[rt][j], fmaxf(best[rt][j], s));
                bidx[rt][j] = (s < best[rt][j]) ? kk : bidx[rt][j];
                best[rt][j] = nb; sec[rt][j] = ns;
            }
    }

#pragma unroll
    for (int st = 1; st < 16; st <<= 1) {
#pragma unroll
        for (int rt = 0; rt < 2; ++rt)
#pragma unroll
            for (int j = 0; j < 4; ++j) {
                float ob = __shfl_xor(best[rt][j], st);
                float os = __shfl_xor(sec[rt][j], st);
                int oi = __shfl_xor(bidx[rt][j], st);
                if (ob < best[rt][j] || (ob == best[rt][j] && oi < bidx[rt][j])) {
                    sec[rt][j] = fminf(best[rt][j], os);
                    best[rt][j] = ob; bidx[rt][j] = oi;
                } else {
                    sec[rt][j] = fminf(sec[rt][j], ob);
                }
            }
    }

    if (m == 0) {   // C/D row = kq*4 + j; publish to LDS + out_idx
#pragma unroll
        for (int rt = 0; rt < 2; ++rt)
#pragma unroll
            for (int j = 0; j < 4; ++j) {
                int r = w * 32 + rt * 16 + kq * 4 + j;
                int id = (sec[rt][j] - best[rt][j] <= MARGIN) ? -1 : bidx[rt][j];
                idx_s[r] = id;
                out_idx[rbase + r] = (float)id;   // sentinel -> refine overwrites
            }
    }
    // same-wave LDS write->read: ordered by program order + lgkmcnt (no barrier)

    // ---- fused epilogue (r12's batched 8-deep-ILP body, per wave) ----------
    const int g = lane >> 4, l16 = lane & 15;
    const long wbase = rbase + w * 32;
    int idxi = (lane < 32) ? idx_s[w * 32 + lane] : 0;

    // append flagged rows to the global refine queue
    if (lane < 32 && idxi < 0) {
        unsigned pos = atomicAdd(qcount, 1u);
        if (pos < QCAP) queue[pos] = (unsigned)(wbase + lane);
    }

    float4 xv[8], wv[8];
    int kk2[8];
#pragma unroll
    for (int i = 0; i < 8; ++i) {
        int r2 = g * 8 + i;
        int kf = __shfl(idxi, r2);
        kk2[i] = kf;
        xv[i] = reinterpret_cast<const float4*>(X)[(wbase + r2) * 16 + l16];
        int ksafe = (kf >= 0) ? kf : 0;
        wv[i] = reinterpret_cast<const float4*>(Wf)[(long)ksafe * 16 + l16];
    }

    float ls = 0.f;
#pragma unroll
    for (int i = 0; i < 8; ++i) {
        if (kk2[i] >= 0) {
            float4 o; float t;
            t = wv[i].x - xv[i].x; o.x = xv[i].x + t; ls = fmaf(t, t, ls);
            t = wv[i].y - xv[i].y; o.y = xv[i].y + t; ls = fmaf(t, t, ls);
            t = wv[i].z - xv[i].z; o.z = xv[i].z + t; ls = fmaf(t, t, ls);
            t = wv[i].w - xv[i].w; o.w = xv[i].w + t; ls = fmaf(t, t, ls);
            reinterpret_cast<float4*>(out_q)[(wbase + g * 8 + i) * 16 + l16] = o;
            if (l16 == 0) atomicAdd(&hist8[hstripe + kk2[i]], 1u);
        }
    }

#pragma unroll
    for (int st = 1; st < 64; st <<= 1) ls += __shfl_xor(ls, st);
    if (lane == 0 && ls != 0.f) atomicAdd(&lossp[blockIdx.x & 255], ls);
}

// ---- refine: load-balanced np-exact, W^T in LDS (unchanged, validated) -----
#define WTP 516
__global__ __launch_bounds__(1024) void vq_refine_k(
    const float* __restrict__ X, const float* __restrict__ Wf,
    const float* __restrict__ bnp,
    float* __restrict__ out_q, float* __restrict__ out_idx,
    unsigned* __restrict__ hist8, float* __restrict__ lossp,
    const unsigned* __restrict__ qcount, const unsigned* __restrict__ queue) {
    __shared__ float WT[64 * WTP];   // WT[d][k] = W[k][d], 132KB
    const int tid = threadIdx.x;
    const int lane = tid & 63, wv = tid >> 6;

#pragma unroll
    for (int i = 0; i < 8; ++i) {
        int f = i * 1024 + tid;
        int k = f >> 4, c4 = f & 15;
        float4 v = reinterpret_cast<const float4*>(Wf)[f];
        WT[(c4 * 4 + 0) * WTP + k] = v.x;
        WT[(c4 * 4 + 1) * WTP + k] = v.y;
        WT[(c4 * 4 + 2) * WTP + k] = v.z;
        WT[(c4 * 4 + 3) * WTP + k] = v.w;
    }
    __syncthreads();

    unsigned n = *qcount;
    if (n > QCAP) n = QCAP;
    const int gwave = blockIdx.x * 16 + wv;

    float ls = 0.f;
    for (unsigned j = gwave; j < n; j += 256 * 16) {
        const long row = (long)queue[j];
        const float xv = X[row * DIM + lane];
        float sq = sqr_nf(xv);
        float rr = sq;
#pragma unroll
        for (int t2 = 1; t2 < 8; ++t2) rr += __shfl(sq, (lane & 7) + 8 * t2);
        float t01 = rr + __shfl_xor(rr, 1);
        float t03 = t01 + __shfl_xor(t01, 2);
        float Afull = t03 + __shfl_xor(t03, 4);
        const float A = __shfl(Afull, 0);
        float acc[8];
#pragma unroll
        for (int c = 0; c < 8; ++c) acc[c] = 0.f;
        for (int d = 0; d < 64; ++d) {
            float xd = __shfl(xv, d);
#pragma unroll
            for (int c = 0; c < 8; ++c)
                acc[c] = fmaf(xd, WT[d * WTP + c * 64 + lane], acc[c]);
        }
        float bs = 3e38f;
        int bi = 0;
#pragma unroll
        for (int c = 0; c < 8; ++c) {
            int k = c * 64 + lane;
            float u = A + bnp[k];
            float s2 = u - 2.0f * acc[c];
            if (s2 < bs) { bs = s2; bi = k; }
        }
#pragma unroll
        for (int st = 1; st < 64; st <<= 1) {
            float ob = __shfl_xor(bs, st);
            int oi = __shfl_xor(bi, st);
            if (ob < bs || (ob == bs && oi < bi)) { bs = ob; bi = oi; }
        }
        const int k = bi;
        if (lane == 0) {
            out_idx[row] = (float)k;
            atomicAdd(&hist8[(j & 7) * KCODES + k], 1u);
        }
        float qv = WT[lane * WTP + k];
        float diff = qv - xv;
        out_q[row * DIM + lane] = xv + diff;
        ls = fmaf(diff, diff, ls);
    }

#pragma unroll
    for (int st = 1; st < 64; st <<= 1) ls += __shfl_xor(ls, st);
    if (lane == 0 && ls != 0.f) atomicAdd(&lossp[gwave & 255], ls);
}

__global__ __launch_bounds__(512) void vq_finalize_k(
    const unsigned* __restrict__ hist8, const float* __restrict__ lossp,
    float* __restrict__ out_loss, float* __restrict__ out_perp) {
    __shared__ float red[512];
    int t = threadIdx.x;
    unsigned c = 0;
#pragma unroll
    for (int s = 0; s < 8; ++s) c += hist8[s * KCODES + t];
    float p = (float)c * (1.0f / (float)N_ROWS);
    red[t] = p * logf(p + 1e-10f);
    __syncthreads();
    for (int off = 256; off; off >>= 1) {
        if (t < off) red[t] += red[t + off];
        __syncthreads();
    }
    if (t == 0) *out_perp = expf(-red[0]);
    __syncthreads();
    red[t] = (t < 256) ? lossp[t] : 0.f;
    __syncthreads();
    for (int off = 256; off; off >>= 1) {
        if (t < off) red[t] += red[t + off];
        __syncthreads();
    }
    if (t == 0) {
        float m = red[0] / (float)(N_ROWS * DIM);
        *out_loss = m + 0.25f * m;
    }
}

extern "C" void kernel_launch(void* const* d_in, const int* in_sizes, int n_in,
                              void* d_out, int out_size, void* d_ws, size_t ws_size,
                              hipStream_t stream) {
    const float* X = (const float*)d_in[0];
    const float* Wf = (const float*)d_in[1];

    float* out = (float*)d_out;
    float* out_loss = out;
    float* out_q = out + 1;
    float* out_perp = out + 1 + (long)N_ROWS * DIM;
    float* out_idx = out + 2 + (long)N_ROWS * DIM;

    unsigned* wsu = (unsigned*)d_ws;
    float* lossp = (float*)d_ws;                    // [0..256)
    unsigned* hist8 = wsu + 256;                    // [256..4352)
    unsigned* qcount = wsu + 4352;                  // [4352]
    unsigned* queue = wsu + 4360;                   // [4360..37128)
    float* bnp = (float*)(wsu + 37128);             // [37128..37640)
    unsigned short* wfrag = (unsigned short*)(wsu + 37640);  // [37640..70408)

    hipMemsetAsync(d_ws, 0, 17424, stream);         // lossp + hist8 + qcount
    vq_wprep_k<<<2, 256, 0, stream>>>(Wf, wfrag, bnp);
    vq_main_k<<<N_ROWS / 128, 256, 0, stream>>>(X, Wf, wfrag, bnp,
                                                out_q, out_idx,
                                                hist8, lossp, qcount, queue);
    vq_refine_k<<<256, 1024, 0, stream>>>(X, Wf, bnp, out_q, out_idx,
                                          hist8, lossp, qcount, queue);
    vq_finalize_k<<<1, 512, 0, stream>>>(hist8, lossp, out_loss, out_perp);
}